// Round 2
// baseline (1607.557 us; speedup 1.0000x reference)
//
#include <hip/hip_runtime.h>

// Batched Kalman filter: one thread per batch element, sequential over T.
// State per thread: mu (4), Sig upper-triangle (10). A is sparse:
// A = [[a,0,c,0],[0,a,0,c],[d,0,1,0],[0,d,0,1]], a=0.999, c=-0.01, d=0.01.
// Q = diag(1,1,0,0). Obs = rows 2,3 of state.

__global__ __launch_bounds__(64, 1)
void kalman_seq(const float* __restrict__ zl,
                const float* __restrict__ mu0,
                float* __restrict__ out,
                int N, int T)
{
    const int n = blockIdx.x * 64 + threadIdx.x;
    if (n >= N) return;

    const float a  = 0.999f;   // 1 - (B/M)*DT
    const float cA = -0.01f;   // -(K/M)*DT
    const float dA = 0.01f;    // DT

    float4 m4 = reinterpret_cast<const float4*>(mu0)[n];
    float m0 = m4.x, m1 = m4.y, m2 = m4.z, m3 = m4.w;

    // Sig = I
    float P00=1.f, P01=0.f, P02=0.f, P03=0.f;
    float P11=1.f, P12=0.f, P13=0.f;
    float P22=1.f, P23=0.f, P33=1.f;

    const long strideZ = (long)N * 5;
    const long strideY = (long)N * 2;
    const float* zp = zl + (long)n * 5;
    float* yp = out + (long)n * 2;

    // 2-deep software prefetch pipeline for z/Lh
    float z0, z1, L0, L1, L2;          // current (t)
    float nz0, nz1, nL0, nL1, nL2;     // next (t+1)
    z0 = zp[0]; z1 = zp[1]; L0 = zp[2]; L1 = zp[3]; L2 = zp[4];
    nz0 = nz1 = nL0 = nL1 = nL2 = 0.f;
    if (T > 1) {
        const float* q = zp + strideZ;
        nz0 = q[0]; nz1 = q[1]; nL0 = q[2]; nL1 = q[3]; nL2 = q[4];
    }
    const float* qp = zp + 2 * strideZ;

    for (int t = 0; t < T; ++t) {
        // prefetch t+2
        float pz0 = 0.f, pz1 = 0.f, pL0 = 0.f, pL1 = 0.f, pL2 = 0.f;
        if (t + 2 < T) {
            pz0 = qp[0]; pz1 = qp[1]; pL0 = qp[2]; pL1 = qp[3]; pL2 = qp[4];
            qp += strideZ;
        }

        // ---- predict mean: mp = A mu ----
        float mp0 = a * m0 + cA * m2;
        float mp1 = a * m1 + cA * m3;
        float mp2 = dA * m0 + m2;
        float mp3 = dA * m1 + m3;

        // ---- M = A P (P symmetric, use upper entries) ----
        float M00 = a * P00 + cA * P02;
        float M01 = a * P01 + cA * P12;
        float M02 = a * P02 + cA * P22;
        float M03 = a * P03 + cA * P23;
        float M10 = a * P01 + cA * P03;
        float M11 = a * P11 + cA * P13;
        float M12 = a * P12 + cA * P23;
        float M13 = a * P13 + cA * P33;
        float M20 = dA * P00 + P02;
        float M21 = dA * P01 + P12;
        float M22 = dA * P02 + P22;
        float M23 = dA * P03 + P23;
        float M30 = dA * P01 + P03;
        float M31 = dA * P11 + P13;
        float M33 = dA * P13 + P33;

        // ---- Q = M A^T + diag(1,1,0,0), upper triangle ----
        float Q00 = a * M00 + cA * M02 + 1.0f;
        float Q01 = a * M01 + cA * M03;
        float Q02 = dA * M00 + M02;
        float Q03 = dA * M01 + M03;
        float Q11 = a * M11 + cA * M13 + 1.0f;
        float Q12 = dA * M10 + M12;
        float Q13 = dA * M11 + M13;
        float Q22 = dA * M20 + M22;
        float Q23 = dA * M21 + M23;
        float Q33 = dA * M31 + M33;

        // ---- measurement noise R from Cholesky factors ----
        float l00 = __expf(L0);
        float l10 = L1;
        float l11 = __expf(L2);
        float R00 = l00 * l00;
        float R01 = l00 * l10;
        float R11 = l10 * l10 + l11 * l11;

        // ---- innovation covariance S (2x2 sym) and inverse ----
        float S00 = Q22 + R00;
        float S01 = Q23 + R01;
        float S11 = Q33 + R11;
        float det = S00 * S11 - S01 * S01;
        float inv = __builtin_amdgcn_rcpf(det);
        float iS00 = S11 * inv;
        float iS01 = -S01 * inv;
        float iS11 = S00 * inv;

        // ---- Kalman gain K = Q[:,2:4] @ Sinv ----
        float K00 = Q02 * iS00 + Q03 * iS01;
        float K01 = Q02 * iS01 + Q03 * iS11;
        float K10 = Q12 * iS00 + Q13 * iS01;
        float K11 = Q12 * iS01 + Q13 * iS11;
        float K20 = Q22 * iS00 + Q23 * iS01;
        float K21 = Q22 * iS01 + Q23 * iS11;
        float K30 = Q23 * iS00 + Q33 * iS01;
        float K31 = Q23 * iS01 + Q33 * iS11;

        // ---- mean update ----
        float in0 = z0 - mp2;
        float in1 = z1 - mp3;
        m0 = mp0 + K00 * in0 + K01 * in1;
        m1 = mp1 + K10 * in0 + K11 * in1;
        m2 = mp2 + K20 * in0 + K21 * in1;
        m3 = mp3 + K30 * in0 + K31 * in1;

        // ---- covariance update: P = Q - K * Q[2:4,:] ----
        P00 = Q00 - K00 * Q02 - K01 * Q03;
        P01 = Q01 - K00 * Q12 - K01 * Q13;
        P02 = Q02 - K00 * Q22 - K01 * Q23;
        P03 = Q03 - K00 * Q23 - K01 * Q33;
        P11 = Q11 - K10 * Q12 - K11 * Q13;
        P12 = Q12 - K10 * Q22 - K11 * Q23;
        P13 = Q13 - K10 * Q23 - K11 * Q33;
        P22 = Q22 - K20 * Q22 - K21 * Q23;
        P23 = Q23 - K20 * Q23 - K21 * Q33;
        P33 = Q33 - K30 * Q23 - K31 * Q33;

        // ---- emit y = mu[2:4] ----
        reinterpret_cast<float2*>(yp)[0] = make_float2(m2, m3);
        yp += strideY;

        // rotate prefetch pipeline
        z0 = nz0; z1 = nz1; L0 = nL0; L1 = nL1; L2 = nL2;
        nz0 = pz0; nz1 = pz1; nL0 = pL0; nL1 = pL1; nL2 = pL2;
    }
}

extern "C" void kernel_launch(void* const* d_in, const int* in_sizes, int n_in,
                              void* d_out, int out_size, void* d_ws, size_t ws_size,
                              hipStream_t stream) {
    const float* zl  = (const float*)d_in[0];
    const float* mu0 = (const float*)d_in[1];
    float* out = (float*)d_out;

    int N = in_sizes[1] / 4;             // 4096
    int T = in_sizes[0] / (N * 5);       // 2048

    int block = 64;
    int grid = (N + block - 1) / block;  // 64 blocks -> 64 CUs, 1 wave each
    kalman_seq<<<grid, block, 0, stream>>>(zl, mu0, out, N, T);
}